// Round 1
// baseline (1293.450 us; speedup 1.0000x reference)
//
#include <hip/hip_runtime.h>
#include <math.h>

// ============================================================================
// SimpleNTLBGModel: video frame top-6 selection + cross-attn + classifier
// Shapes: B=32 T=4096 D_IN=768 D=512 H=8 hd=64 K=6 L=512 V=1000
// Pipeline:
//   1. wenct_k      : W_enc [768,512] f32 -> WencT [512,768] f16 (transposed)
//   2. score_gemm   : scores[b,t] = relu(vf@W_enc+b_enc)@W_sel + b_sel  (f16 MFMA, fused)
//   3. topk16       : per batch, top-16 candidate frames by approx score
//   4. rescore      : exact fp32 ve rows + scores for the 16 candidates
//   5. select6      : stable top-6 by exact score (lower-index tiebreak) -> reps out
//   6. kv_proj      : k,v for 6 reps (scale folded into k)
//   7. qemb_k       : Q_emb = emb@W_q + b_q  (1000 vocab rows; q becomes a gather)
//   8. woc_k        : W_ocT = (W_o@W_cls)^T f16 (folds out the W_o GEMM)
//   9. boc_k        : b_oc = b_o@W_cls + b_cls (padded to 1024)
//  10. ctx_kernel   : per-token K=6 attention -> CTX f16 [16384,512]
//  11. logits_gemm  : CTX @ W_ocT + b_oc -> d_out (f16 MFMA)
// ============================================================================

#define DEV __device__ __forceinline__

typedef _Float16 half8 __attribute__((ext_vector_type(8)));
typedef float f32x4v __attribute__((ext_vector_type(4)));

DEV unsigned short f2h_bits(float f) {
  union { _Float16 h; unsigned short u; } cv;
  cv.h = (_Float16)f;
  return cv.u;
}

// ---------------------------------------------------------------------------
// 1. W_enc [768,512] f32 -> WencT [512,768] f16
__global__ void wenct_k(const float* __restrict__ W_enc,
                        unsigned short* __restrict__ WencT) {
  int gid = blockIdx.x * 256 + threadIdx.x;   // 0 .. 768*512-1
  int k = gid >> 9, n = gid & 511;
  WencT[(size_t)n * 768 + k] = f2h_bits(W_enc[gid]);
}

// ---------------------------------------------------------------------------
// 2. Big fused GEMM: per 64-row tile compute all 512 cols, epilogue reduces to
//    a single score per row. 512 threads = 8 waves; wave w owns cols [w*64,w*64+64).
__global__ __launch_bounds__(512, 2) void score_gemm(
    const float* __restrict__ vf, const unsigned short* __restrict__ WencT,
    const float* __restrict__ b_enc, const float* __restrict__ W_sel,
    const float* __restrict__ b_sel, float* __restrict__ scores) {
  __shared__ unsigned short As[64 * 32];    // [m][k] f16
  __shared__ unsigned short Bs[512 * 32];   // [n][k] f16 (B pre-transposed)
  __shared__ float red[8 * 64];

  const int tid = threadIdx.x;
  const int w = tid >> 6, lane = tid & 63;
  const int quad = lane >> 4, l15 = lane & 15;
  const int rowBase = blockIdx.x * 64;

  f32x4v acc[4][4];
#pragma unroll
  for (int i = 0; i < 4; ++i)
#pragma unroll
    for (int j = 0; j < 4; ++j) acc[i][j] = (f32x4v){0.f, 0.f, 0.f, 0.f};

  const int arow = tid >> 3, aseg = tid & 7;
  const float* aSrc = vf + (size_t)(rowBase + arow) * 768 + aseg * 4;
  unsigned int* aDst = (unsigned int*)&As[arow * 32 + aseg * 4];

  for (int kk = 0; kk < 24; ++kk) {
    const int k0 = kk * 32;
    __syncthreads();
    // stage A: fp32 -> fp16, 4 elems/thread
    float4 fa = *(const float4*)(aSrc + k0);
    aDst[0] = (unsigned int)f2h_bits(fa.x) | ((unsigned int)f2h_bits(fa.y) << 16);
    aDst[1] = (unsigned int)f2h_bits(fa.z) | ((unsigned int)f2h_bits(fa.w) << 16);
    // stage B: straight f16 copy, 16B/chunk
#pragma unroll
    for (int it = 0; it < 4; ++it) {
      int q = tid + it * 512;               // 0..2047 chunks of 8 f16
      int n = q >> 2, k8 = (q & 3) * 8;
      *(uint4*)&Bs[q * 8] = *(const uint4*)(WencT + (size_t)n * 768 + k0 + k8);
    }
    __syncthreads();
    half8 af[4], bfr[4];
#pragma unroll
    for (int i = 0; i < 4; ++i)
      af[i] = *(const half8*)&As[(16 * i + l15) * 32 + quad * 8];
#pragma unroll
    for (int j = 0; j < 4; ++j)
      bfr[j] = *(const half8*)&Bs[(w * 64 + 16 * j + l15) * 32 + quad * 8];
#pragma unroll
    for (int i = 0; i < 4; ++i)
#pragma unroll
      for (int j = 0; j < 4; ++j)
        acc[i][j] = __builtin_amdgcn_mfma_f32_16x16x32_f16(af[i], bfr[j], acc[i][j], 0, 0, 0);
  }

  // epilogue: (x + b_enc) -> relu -> * W_sel -> reduce over cols
  float be[4], wsv[4];
#pragma unroll
  for (int j = 0; j < 4; ++j) {
    int col = w * 64 + 16 * j + l15;
    be[j] = b_enc[col];
    wsv[j] = W_sel[col];
  }
  float part[16];
#pragma unroll
  for (int x = 0; x < 16; ++x) part[x] = 0.f;
#pragma unroll
  for (int i = 0; i < 4; ++i)
#pragma unroll
    for (int j = 0; j < 4; ++j)
#pragma unroll
      for (int r = 0; r < 4; ++r) {
        float v = acc[i][j][r] + be[j];     // C/D layout: row=16i+quad*4+r, col=w*64+16j+l15
        v = fmaxf(v, 0.f);
        part[i * 4 + r] += v * wsv[j];
      }
  // reduce over the 16 lanes (l15) holding different cols of the same rows
#pragma unroll
  for (int m = 1; m < 16; m <<= 1)
#pragma unroll
    for (int x = 0; x < 16; ++x) part[x] += __shfl_xor(part[x], m);
  if (l15 == 0) {
#pragma unroll
    for (int i = 0; i < 4; ++i)
#pragma unroll
      for (int r = 0; r < 4; ++r)
        red[w * 64 + 16 * i + quad * 4 + r] = part[i * 4 + r];
  }
  __syncthreads();
  if (tid < 64) {
    float s = 0.f;
#pragma unroll
    for (int ww = 0; ww < 8; ++ww) s += red[ww * 64 + tid];
    scores[rowBase + tid] = s + b_sel[0];
  }
}

// ---------------------------------------------------------------------------
// 3. per-batch top-16 candidates (approx scores). One block per batch.
__global__ __launch_bounds__(256) void topk16(const float* __restrict__ scores,
                                              int* __restrict__ cand) {
  __shared__ float sc[4096];
  __shared__ float rv[256];
  __shared__ int ri[256];
  const int b = blockIdx.x, tid = threadIdx.x;
  for (int i = tid; i < 4096; i += 256) sc[i] = scores[b * 4096 + i];
  __syncthreads();
  for (int p = 0; p < 16; ++p) {
    float best = -3.0e38f;
    int bi = 1 << 30;
    for (int i = tid; i < 4096; i += 256) {
      float v = sc[i];
      if (v > best) { best = v; bi = i; }
    }
    rv[tid] = best; ri[tid] = bi;
    __syncthreads();
    for (int s = 128; s > 0; s >>= 1) {
      if (tid < s) {
        float v = rv[tid + s]; int j = ri[tid + s];
        if (v > rv[tid] || (v == rv[tid] && j < ri[tid])) { rv[tid] = v; ri[tid] = j; }
      }
      __syncthreads();
    }
    if (tid == 0) { cand[b * 16 + p] = ri[0]; sc[ri[0]] = -3.3e38f; }
    __syncthreads();
  }
}

// ---------------------------------------------------------------------------
// 4. exact fp32 recompute of ve rows + scores for the 16 candidates / batch.
__global__ __launch_bounds__(256) void rescore(
    const float* __restrict__ vf, const int* __restrict__ cand,
    const float* __restrict__ W_enc, const float* __restrict__ b_enc,
    const float* __restrict__ W_sel, const float* __restrict__ b_sel,
    float* __restrict__ veC, float* __restrict__ exsc) {
  __shared__ float vfs[16][768];            // 48KB
  __shared__ float redl[16 * 4];
  const int b = blockIdx.x, tid = threadIdx.x;
  for (int c = 0; c < 16; ++c) {
    int t = cand[b * 16 + c];
    const float* src = vf + ((size_t)b * 4096 + t) * 768;
    for (int i = tid; i < 768; i += 256) vfs[c][i] = src[i];
  }
  __syncthreads();
  const int j0 = tid, j1 = tid + 256;
  float a0[16], a1[16];
#pragma unroll
  for (int c = 0; c < 16; ++c) { a0[c] = 0.f; a1[c] = 0.f; }
  for (int i = 0; i < 768; ++i) {
    float w0 = W_enc[i * 512 + j0], w1 = W_enc[i * 512 + j1];
#pragma unroll
    for (int c = 0; c < 16; ++c) {
      float x = vfs[c][i];
      a0[c] += x * w0;
      a1[c] += x * w1;
    }
  }
  float ws0 = W_sel[j0], ws1 = W_sel[j1];
  float be0 = b_enc[j0], be1 = b_enc[j1];
  float s[16];
#pragma unroll
  for (int c = 0; c < 16; ++c) {
    float v0 = fmaxf(a0[c] + be0, 0.f);
    float v1 = fmaxf(a1[c] + be1, 0.f);
    veC[((size_t)b * 16 + c) * 512 + j0] = v0;
    veC[((size_t)b * 16 + c) * 512 + j1] = v1;
    s[c] = v0 * ws0 + v1 * ws1;
  }
#pragma unroll
  for (int m = 1; m < 64; m <<= 1)
#pragma unroll
    for (int c = 0; c < 16; ++c) s[c] += __shfl_xor(s[c], m);
  int w = tid >> 6;
  if ((tid & 63) == 0) {
#pragma unroll
    for (int c = 0; c < 16; ++c) redl[c * 4 + w] = s[c];
  }
  __syncthreads();
  if (tid < 16)
    exsc[b * 16 + tid] = redl[tid * 4 + 0] + redl[tid * 4 + 1] +
                         redl[tid * 4 + 2] + redl[tid * 4 + 3] + b_sel[0];
}

// ---------------------------------------------------------------------------
// 5. stable top-6 by exact score (desc; ties -> lower frame index) + reps out.
__global__ __launch_bounds__(256) void select6(
    const float* __restrict__ exsc, const int* __restrict__ cand,
    const float* __restrict__ veC, int* __restrict__ sel,
    float* __restrict__ repsOut) {
  __shared__ int selL[6];
  const int b = blockIdx.x, tid = threadIdx.x;
  if (tid == 0) {
    float v[16]; int idx[16]; bool used[16];
    for (int c = 0; c < 16; ++c) {
      v[c] = exsc[b * 16 + c];
      idx[c] = cand[b * 16 + c];
      used[c] = false;
    }
    for (int r = 0; r < 6; ++r) {
      int bi = -1;
      for (int c = 0; c < 16; ++c) {
        if (used[c]) continue;
        if (bi < 0 || v[c] > v[bi] || (v[c] == v[bi] && idx[c] < idx[bi])) bi = c;
      }
      used[bi] = true;
      selL[r] = bi;
      sel[b * 6 + r] = bi;
    }
  }
  __syncthreads();
  for (int r = 0; r < 6; ++r) {
    int c = selL[r];
    for (int i = tid; i < 512; i += 256)
      repsOut[((size_t)b * 6 + r) * 512 + i] = veC[((size_t)b * 16 + c) * 512 + i];
  }
}

// ---------------------------------------------------------------------------
// 6. k/v projections of reps; 1/sqrt(64) folded into k.
__global__ __launch_bounds__(256) void kv_proj(
    const int* __restrict__ sel, const float* __restrict__ veC,
    const float* __restrict__ W_k, const float* __restrict__ W_v,
    const float* __restrict__ b_k, const float* __restrict__ b_v,
    float* __restrict__ Ks, float* __restrict__ Vs) {
  __shared__ float rep[512];
  const int br = blockIdx.x;                // b*6 + r
  const int b = br / 6;
  const int tid = threadIdx.x;
  const int c = sel[br];
  for (int i = tid; i < 512; i += 256) rep[i] = veC[((size_t)b * 16 + c) * 512 + i];
  __syncthreads();
  const int j0 = tid, j1 = tid + 256;
  float k0 = 0.f, k1 = 0.f, v0 = 0.f, v1 = 0.f;
  for (int m = 0; m < 512; ++m) {
    float x = rep[m];
    k0 += x * W_k[m * 512 + j0];
    k1 += x * W_k[m * 512 + j1];
    v0 += x * W_v[m * 512 + j0];
    v1 += x * W_v[m * 512 + j1];
  }
  Ks[(size_t)br * 512 + j0] = (k0 + b_k[j0]) * 0.125f;
  Ks[(size_t)br * 512 + j1] = (k1 + b_k[j1]) * 0.125f;
  Vs[(size_t)br * 512 + j0] = v0 + b_v[j0];
  Vs[(size_t)br * 512 + j1] = v1 + b_v[j1];
}

// ---------------------------------------------------------------------------
// 7. Q_emb = emb@W_q + b_q   (8 vocab rows per block)
__global__ __launch_bounds__(256) void qemb_k(
    const float* __restrict__ emb, const float* __restrict__ W_q,
    const float* __restrict__ b_q, float* __restrict__ Qe) {
  __shared__ float er[8 * 512];
  const int r0 = blockIdx.x * 8, tid = threadIdx.x;
  for (int i = tid; i < 4096; i += 256) er[i] = emb[(size_t)r0 * 512 + i];
  __syncthreads();
  const int j0 = tid, j1 = tid + 256;
  float a0[8], a1[8];
#pragma unroll
  for (int r = 0; r < 8; ++r) { a0[r] = 0.f; a1[r] = 0.f; }
  for (int i = 0; i < 512; ++i) {
    float w0 = W_q[i * 512 + j0], w1 = W_q[i * 512 + j1];
#pragma unroll
    for (int r = 0; r < 8; ++r) {
      a0[r] += er[r * 512 + i] * w0;
      a1[r] += er[r * 512 + i] * w1;
    }
  }
  float bq0 = b_q[j0], bq1 = b_q[j1];
#pragma unroll
  for (int r = 0; r < 8; ++r) {
    Qe[(size_t)(r0 + r) * 512 + j0] = a0[r] + bq0;
    Qe[(size_t)(r0 + r) * 512 + j1] = a1[r] + bq1;
  }
}

// ---------------------------------------------------------------------------
// 8. W_ocT[n][k] = (W_o@W_cls)[k][n] as f16, n padded to 1024.
__global__ __launch_bounds__(256) void woc_k(
    const float* __restrict__ W_o, const float* __restrict__ W_cls,
    unsigned short* __restrict__ WocT) {
  __shared__ float wr[8 * 512];
  const int i0 = blockIdx.x * 8, tid = threadIdx.x;
  for (int i = tid; i < 4096; i += 256) wr[i] = W_o[(size_t)i0 * 512 + i];
  __syncthreads();
  float a[8][4];
#pragma unroll
  for (int r = 0; r < 8; ++r)
#pragma unroll
    for (int c = 0; c < 4; ++c) a[r][c] = 0.f;
  for (int m = 0; m < 512; ++m) {
    float wc[4];
#pragma unroll
    for (int c = 0; c < 4; ++c) {
      int j = tid + c * 256;
      wc[c] = (j < 1000) ? W_cls[(size_t)m * 1000 + j] : 0.f;
    }
#pragma unroll
    for (int r = 0; r < 8; ++r) {
      float x = wr[r * 512 + m];
#pragma unroll
      for (int c = 0; c < 4; ++c) a[r][c] += x * wc[c];
    }
  }
#pragma unroll
  for (int r = 0; r < 8; ++r)
#pragma unroll
    for (int c = 0; c < 4; ++c) {
      int j = tid + c * 256;
      if (j < 1000) WocT[(size_t)j * 512 + i0 + r] = f2h_bits(a[r][c]);
    }
  if (blockIdx.x == 0) {  // zero pad rows 1000..1023
    for (int i = tid; i < 24 * 512; i += 256) WocT[512000 + i] = 0;
  }
}

// ---------------------------------------------------------------------------
// 9. b_oc = b_o@W_cls + b_cls, padded to 1024 with zeros.
__global__ void boc_k(const float* __restrict__ b_o, const float* __restrict__ W_cls,
                      const float* __restrict__ b_cls, float* __restrict__ boc) {
  int j = blockIdx.x * 256 + threadIdx.x;   // 0..1023
  float s = 0.f;
  if (j < 1000) {
    for (int m = 0; m < 512; ++m) s += b_o[m] * W_cls[(size_t)m * 1000 + j];
    s += b_cls[j];
  }
  boc[j] = s;
}

// ---------------------------------------------------------------------------
// 10. per-token attention over K=6 keys; one wave per token.
__global__ __launch_bounds__(256) void ctx_kernel(
    const int* __restrict__ ids, const float* __restrict__ Qe,
    const float* __restrict__ Ks, const float* __restrict__ Vs,
    unsigned short* __restrict__ CTX) {
  const int token = blockIdx.x * 4 + (threadIdx.x >> 6);
  const int lane = threadIdx.x & 63;
  const int b = token >> 9;                 // L = 512
  const int id = ids[token];
  float q[8];
#pragma unroll
  for (int h = 0; h < 8; ++h) q[h] = Qe[(size_t)id * 512 + h * 64 + lane];
  float s[8][6];
#pragma unroll
  for (int kk = 0; kk < 6; ++kk) {
    const float* kp = Ks + ((size_t)b * 6 + kk) * 512 + lane;
    float p[8];
#pragma unroll
    for (int h = 0; h < 8; ++h) p[h] = q[h] * kp[h * 64];
#pragma unroll
    for (int m = 1; m < 64; m <<= 1)
#pragma unroll
      for (int h = 0; h < 8; ++h) p[h] += __shfl_xor(p[h], m);
#pragma unroll
    for (int h = 0; h < 8; ++h) s[h][kk] = p[h];
  }
  const float* vbase = Vs + (size_t)b * 6 * 512 + lane;
#pragma unroll
  for (int h = 0; h < 8; ++h) {
    float mx = s[h][0];
#pragma unroll
    for (int kk = 1; kk < 6; ++kk) mx = fmaxf(mx, s[h][kk]);
    float e[6], sum = 0.f;
#pragma unroll
    for (int kk = 0; kk < 6; ++kk) { e[kk] = __expf(s[h][kk] - mx); sum += e[kk]; }
    float c = 0.f;
#pragma unroll
    for (int kk = 0; kk < 6; ++kk) c += e[kk] * vbase[(size_t)kk * 512 + h * 64];
    c *= (1.f / sum);
    CTX[(size_t)token * 512 + h * 64 + lane] = f2h_bits(c);
  }
}

// ---------------------------------------------------------------------------
// 11. logits = CTX @ W_oc + b_oc  -> d_out fp32. Same MFMA structure.
__global__ __launch_bounds__(512, 2) void logits_gemm(
    const unsigned short* __restrict__ CTX, const unsigned short* __restrict__ WocT,
    const float* __restrict__ boc, float* __restrict__ out) {
  __shared__ unsigned short As[64 * 32];
  __shared__ unsigned short Bs[512 * 32];
  const int tid = threadIdx.x;
  const int w = tid >> 6, lane = tid & 63;
  const int quad = lane >> 4, l15 = lane & 15;
  const int rowBase = blockIdx.x * 64;
  const int n0 = blockIdx.y * 512;

  f32x4v acc[4][4];
#pragma unroll
  for (int i = 0; i < 4; ++i)
#pragma unroll
    for (int j = 0; j < 4; ++j) acc[i][j] = (f32x4v){0.f, 0.f, 0.f, 0.f};

  for (int kk = 0; kk < 16; ++kk) {
    const int k0 = kk * 32;
    __syncthreads();
    if (tid < 256) {                         // A tile 64x32 f16 = 256 chunks
      int m = tid >> 2, k8 = (tid & 3) * 8;
      *(uint4*)&As[tid * 8] = *(const uint4*)(CTX + (size_t)(rowBase + m) * 512 + k0 + k8);
    }
#pragma unroll
    for (int it = 0; it < 4; ++it) {         // B tile 512x32 f16 = 2048 chunks
      int q = tid + it * 512;
      int n = q >> 2, k8 = (q & 3) * 8;
      *(uint4*)&Bs[q * 8] = *(const uint4*)(WocT + (size_t)(n0 + n) * 512 + k0 + k8);
    }
    __syncthreads();
    half8 af[4], bfr[4];
#pragma unroll
    for (int i = 0; i < 4; ++i)
      af[i] = *(const half8*)&As[(16 * i + l15) * 32 + quad * 8];
#pragma unroll
    for (int j = 0; j < 4; ++j)
      bfr[j] = *(const half8*)&Bs[(w * 64 + 16 * j + l15) * 32 + quad * 8];
#pragma unroll
    for (int i = 0; i < 4; ++i)
#pragma unroll
      for (int j = 0; j < 4; ++j)
        acc[i][j] = __builtin_amdgcn_mfma_f32_16x16x32_f16(af[i], bfr[j], acc[i][j], 0, 0, 0);
  }

  float bo[4];
#pragma unroll
  for (int j = 0; j < 4; ++j) bo[j] = boc[n0 + w * 64 + 16 * j + l15];
#pragma unroll
  for (int i = 0; i < 4; ++i)
#pragma unroll
    for (int j = 0; j < 4; ++j)
#pragma unroll
      for (int r = 0; r < 4; ++r) {
        int token = rowBase + 16 * i + quad * 4 + r;
        int col = n0 + w * 64 + 16 * j + l15;
        if (col < 1000) out[(size_t)token * 1000 + col] = acc[i][j][r] + bo[j];
      }
}

// ===========================================================================
extern "C" void kernel_launch(void* const* d_in, const int* in_sizes, int n_in,
                              void* d_out, int out_size, void* d_ws, size_t ws_size,
                              hipStream_t stream) {
  (void)in_sizes; (void)n_in; (void)out_size; (void)ws_size;
  const float* vf    = (const float*)d_in[0];
  const int*   ids   = (const int*)d_in[1];
  // d_in[2] attention_mask: unused by reference
  const float* W_enc = (const float*)d_in[3];
  const float* b_enc = (const float*)d_in[4];
  const float* W_sel = (const float*)d_in[5];
  const float* b_sel = (const float*)d_in[6];
  const float* emb   = (const float*)d_in[7];
  const float* W_q   = (const float*)d_in[8];
  const float* W_k   = (const float*)d_in[9];
  const float* W_v   = (const float*)d_in[10];
  const float* b_q   = (const float*)d_in[11];
  const float* b_k   = (const float*)d_in[12];
  const float* b_v   = (const float*)d_in[13];
  const float* W_o   = (const float*)d_in[14];
  const float* b_o   = (const float*)d_in[15];
  const float* W_cls = (const float*)d_in[16];
  const float* b_cls = (const float*)d_in[17];

  float* out = (float*)d_out;                  // logits [32*512*1000]
  float* reps_out = out + (size_t)16384000;    // reps   [32*6*512]

  // workspace carve-up (~23 MB)
  char* p = (char*)d_ws;
  auto nxt = [&](size_t bytes) -> char* {
    char* q = p;
    p += (bytes + 255) & ~(size_t)255;
    return q;
  };
  unsigned short* WencT = (unsigned short*)nxt((size_t)512 * 768 * 2);
  unsigned short* WocT  = (unsigned short*)nxt((size_t)1024 * 512 * 2);
  unsigned short* CTX   = (unsigned short*)nxt((size_t)16384 * 512 * 2);
  float* scores = (float*)nxt((size_t)131072 * 4);
  int*   cand   = (int*)nxt((size_t)512 * 4);
  float* exsc   = (float*)nxt((size_t)512 * 4);
  float* veC    = (float*)nxt((size_t)32 * 16 * 512 * 4);
  int*   sel    = (int*)nxt((size_t)192 * 4);
  float* Ks     = (float*)nxt((size_t)98304 * 4);
  float* Vs     = (float*)nxt((size_t)98304 * 4);
  float* Qe     = (float*)nxt((size_t)512000 * 4);
  float* boc    = (float*)nxt((size_t)1024 * 4);

  hipLaunchKernelGGL(wenct_k,     dim3(1536),   dim3(256), 0, stream, W_enc, WencT);
  hipLaunchKernelGGL(score_gemm,  dim3(2048),   dim3(512), 0, stream, vf, WencT, b_enc, W_sel, b_sel, scores);
  hipLaunchKernelGGL(topk16,      dim3(32),     dim3(256), 0, stream, scores, cand);
  hipLaunchKernelGGL(rescore,     dim3(32),     dim3(256), 0, stream, vf, cand, W_enc, b_enc, W_sel, b_sel, veC, exsc);
  hipLaunchKernelGGL(select6,     dim3(32),     dim3(256), 0, stream, exsc, cand, veC, sel, reps_out);
  hipLaunchKernelGGL(kv_proj,     dim3(192),    dim3(256), 0, stream, sel, veC, W_k, W_v, b_k, b_v, Ks, Vs);
  hipLaunchKernelGGL(qemb_k,      dim3(125),    dim3(256), 0, stream, emb, W_q, b_q, Qe);
  hipLaunchKernelGGL(woc_k,       dim3(64),     dim3(256), 0, stream, W_o, W_cls, WocT);
  hipLaunchKernelGGL(boc_k,       dim3(4),      dim3(256), 0, stream, b_o, W_cls, b_cls, boc);
  hipLaunchKernelGGL(ctx_kernel,  dim3(4096),   dim3(256), 0, stream, ids, Qe, Ks, Vs, CTX);
  hipLaunchKernelGGL(logits_gemm, dim3(256, 2), dim3(512), 0, stream, CTX, WocT, boc, out);
}